// Round 11
// baseline (578.799 us; speedup 1.0000x reference)
//
#include <hip/hip_runtime.h>
#include <hip/hip_bf16.h>

#define N_EDGES_C 1000000
#define EDGE_DIM_C 64
#define NODE_DIM_C 64
#define IN_DIM_C   192
#define HID_C      256
#define XPAD 200            // bf16 elems per X row (192+8 pad) -> 400B rows
#define XBUF_SZ 25600       // 64 rows * 400B
#define HS_OFF  51200       // H buffers start after 2 X buffers
#define HBUF_SZ 32768       // 64 rows * 512B (swizzled)
#define T_TILES 5           // tiles of 64 edges; 15625/5 = 3125 blocks

typedef __attribute__((ext_vector_type(8))) short  short8;
typedef __attribute__((ext_vector_type(4))) float  f32x4;

// Workgroup barrier WITHOUT vmcnt drain (orders LDS only; stores and
// not-yet-consumed prefetch loads stay in flight across it -- T4).
#define BAR_LDS() asm volatile("s_waitcnt lgkmcnt(0)\n\ts_barrier" ::: "memory")

__device__ __forceinline__ unsigned short f2bf(float f) {
    union { float f; unsigned u; } v; v.f = f;
    unsigned u = v.u;
    u += 0x7fffu + ((u >> 16) & 1u);   // round-to-nearest-even
    return (unsigned short)(u >> 16);
}

// W1[192][256] -> W1T bf16 [256][192]; W2[256][256] -> W2T bf16 [256][256].
__global__ void prep_weights_kernel(const float* __restrict__ W1,
                                    const float* __restrict__ W2,
                                    unsigned short* __restrict__ W1T,
                                    unsigned short* __restrict__ W2T) {
    int tid = blockIdx.x * 256 + threadIdx.x;
    if (tid < IN_DIM_C * HID_C) {
        int n = tid / IN_DIM_C, k = tid - n * IN_DIM_C;
        W1T[tid] = f2bf(W1[k * HID_C + n]);
    } else {
        int t2 = tid - IN_DIM_C * HID_C;
        if (t2 < HID_C * HID_C) {
            int o = t2 / HID_C, k = t2 - o * HID_C;
            W2T[t2] = f2bf(W2[k * HID_C + o]);
        }
    }
}

// 1024 threads = 16 waves; wave w owns feature slice [w*16, w*16+16) for BOTH
// layers. Pinned weights now cost only 56 VGPR/thread (224KB / 1024 thr), so
// the whole kernel fits ~115 VGPR -> 4 waves/SIMD (vs 2 at 512 thr / 112
// weight VGPR). 2x per-SIMD ILP is the point: R4-R10 proved the limiter is
// exposed latency at 2 lockstep waves/SIMD, not barriers/occupancy/BW.
// Price: each X/H fragment is read by 16 waves instead of 8 (LDS reads 2x).
// Per thread: E row tid>>4 -> direct srcI/dstI idx loads (no bpermute chain).
// Xs and Hs double-buffered -> ONE lgkm-only barrier per tile:
//   issueEV(t+1) | L1(t): Xs[t&1] | epi1 -> Hs[t&1] | write_lds -> Xs[(t+1)&1]
//   | BAR | L2(t): Hs[t&1] + NT stores
__global__ __launch_bounds__(1024, 4) void edge_mlp_kernel(
    const float* __restrict__ E, const float* __restrict__ V,
    const int* __restrict__ srcI, const int* __restrict__ dstI,
    const unsigned short* __restrict__ W1T, const float* __restrict__ b1,
    const unsigned short* __restrict__ W2T, const float* __restrict__ b2,
    float* __restrict__ out)
{
    __shared__ unsigned char smem[HS_OFF + 2 * HBUF_SZ];   // 116736 B
    const int tid = threadIdx.x;
    const int w   = tid >> 6;    // wave 0..15
    const int l   = tid & 63;
    const int lm  = l & 15;
    const int lg  = l >> 4;
    const int r16 = tid >> 4;    // staged row 0..63
    const int c16 = tid & 15;    // float4 column 0..15
    const long block0 = (long)blockIdx.x * (64 * T_TILES);

    // ---- weight fragments -> registers (once per block; 56 VGPR) ----
    short8 wA1[6];               // W1T row w*16+lm, k = kb*32 + lg*8
    short8 wA2[8];               // W2T row w*16+lm
#pragma unroll
    for (int kb = 0; kb < 6; ++kb)
        wA1[kb] = *reinterpret_cast<const short8*>(
            W1T + (size_t)(w * 16 + lm) * IN_DIM_C + kb * 32 + lg * 8);
#pragma unroll
    for (int kb = 0; kb < 8; ++kb)
        wA2[kb] = *reinterpret_cast<const short8*>(
            W2T + (size_t)(w * 16 + lm) * HID_C + kb * 32 + lg * 8);

    // ---- biases (hoisted; 8 VGPR) ----
    const int n0 = w * 16 + lg * 4;          // feature base for epi1/epi2
    const f32x4 b1v = *reinterpret_cast<const f32x4*>(b1 + n0);
    const f32x4 b2v = *reinterpret_cast<const f32x4*>(b2 + n0);

    // ---- reg-staged next-tile data (lives across the barrier) ----
    f32x4 fE, fV0, fV1;          // E row r16; V[src r16]; V[dst r16] (16B each)

    auto issueEV = [&](long tb, int gs, int gd) {
        fE = __builtin_nontemporal_load(reinterpret_cast<const f32x4*>(
            E + (size_t)(tb + r16) * EDGE_DIM_C + c16 * 4));
        fV0 = *reinterpret_cast<const f32x4*>(V + (size_t)gs * NODE_DIM_C + c16 * 4);
        fV1 = *reinterpret_cast<const f32x4*>(V + (size_t)gd * NODE_DIM_C + c16 * 4);
    };

    auto write_lds = [&](int buf) {
        unsigned short* Xs = (unsigned short*)(smem + buf * XBUF_SZ);
        ushort4 a, b, c;
        a.x = f2bf(fE[0]);  a.y = f2bf(fE[1]);  a.z = f2bf(fE[2]);  a.w = f2bf(fE[3]);
        b.x = f2bf(fV0[0]); b.y = f2bf(fV0[1]); b.z = f2bf(fV0[2]); b.w = f2bf(fV0[3]);
        c.x = f2bf(fV1[0]); c.y = f2bf(fV1[1]); c.z = f2bf(fV1[2]); c.w = f2bf(fV1[3]);
        *reinterpret_cast<ushort4*>(&Xs[r16 * XPAD + c16 * 4])       = a;
        *reinterpret_cast<ushort4*>(&Xs[r16 * XPAD + 64 + c16 * 4])  = b;
        *reinterpret_cast<ushort4*>(&Xs[r16 * XPAD + 128 + c16 * 4]) = c;
    };

    // ---- prologue: stage tile 0; prefetch idx for tile 1 ----
    {
        int gs0 = srcI[block0 + r16];
        int gd0 = dstI[block0 + r16];
        issueEV(block0, gs0, gd0);
        write_lds(0);
    }
    int gsN = 0, gdN = 0;
    if (T_TILES > 1) { gsN = srcI[block0 + 64 + r16]; gdN = dstI[block0 + 64 + r16]; }
    BAR_LDS();

#pragma unroll 1
    for (int t = 0; t < T_TILES; ++t) {
        const long tb = block0 + (long)t * 64;
        const int xb = t & 1;

        if (t + 1 < T_TILES) issueEV(tb + 64, gsN, gdN);  // flies under L1/epi1
        if (t + 2 < T_TILES) {
            gsN = srcI[tb + 128 + r16];
            gdN = dstI[tb + 128 + r16];
        }

        // ---------------- Layer 1 (pure reg + LDS) ----------------
        const unsigned short* Xs = (const unsigned short*)(smem + xb * XBUF_SZ);
        f32x4 acc[4];
#pragma unroll
        for (int m = 0; m < 4; ++m) acc[m] = (f32x4){0.f, 0.f, 0.f, 0.f};

#pragma unroll
        for (int kb = 0; kb < 6; ++kb) {
            short8 bx[4];
#pragma unroll
            for (int mt = 0; mt < 4; ++mt)
                bx[mt] = *reinterpret_cast<const short8*>(
                    &Xs[(mt * 16 + lm) * XPAD + kb * 32 + lg * 8]);
#pragma unroll
            for (int mt = 0; mt < 4; ++mt)
                acc[mt] = __builtin_amdgcn_mfma_f32_16x16x32_bf16(
                    wA1[kb], bx[mt], acc[mt], 0, 0, 0);
        }

        // epi1: +b1, relu, bf16 -> Hs[xb] (XOR-swizzled)
        unsigned char* Hb = smem + HS_OFF + xb * HBUF_SZ;
#pragma unroll
        for (int mt = 0; mt < 4; ++mt) {
            f32x4 a = acc[mt];
            ushort4 hb;
            hb.x = f2bf(fmaxf(a[0] + b1v[0], 0.f));
            hb.y = f2bf(fmaxf(a[1] + b1v[1], 0.f));
            hb.z = f2bf(fmaxf(a[2] + b1v[2], 0.f));
            hb.w = f2bf(fmaxf(a[3] + b1v[3], 0.f));
            int m = mt * 16 + lm;
            int addr = m * 512 + ((n0 * 2) ^ (lm << 4));
            *reinterpret_cast<ushort4*>(Hb + addr) = hb;
        }

        if (t + 1 < T_TILES) write_lds(xb ^ 1);           // Xs[(t+1)&1]

        BAR_LDS();    // single barrier per tile: Hs[xb] + Xs[xb^1] ready

        // ---------------- Layer 2 (pure reg + LDS) ----------------
        f32x4 acc2[4];
#pragma unroll
        for (int m = 0; m < 4; ++m) acc2[m] = (f32x4){0.f, 0.f, 0.f, 0.f};

#pragma unroll
        for (int kb = 0; kb < 8; ++kb) {
            short8 bh[4];
#pragma unroll
            for (int mt = 0; mt < 4; ++mt) {
                int m = mt * 16 + lm;
                int addr = m * 512 + (((kb * 32 + lg * 8) * 2) ^ (lm << 4));
                bh[mt] = *reinterpret_cast<const short8*>(Hb + addr);
            }
#pragma unroll
            for (int mt = 0; mt < 4; ++mt)
                acc2[mt] = __builtin_amdgcn_mfma_f32_16x16x32_bf16(
                    wA2[kb], bh[mt], acc2[mt], 0, 0, 0);
        }

        // epi2: +b2, coalesced NT float4 store (never waited in-loop)
#pragma unroll
        for (int mt = 0; mt < 4; ++mt) {
            f32x4 a = acc2[mt];
            f32x4 r;
            r[0] = a[0] + b2v[0];
            r[1] = a[1] + b2v[1];
            r[2] = a[2] + b2v[2];
            r[3] = a[3] + b2v[3];
            __builtin_nontemporal_store(r, reinterpret_cast<f32x4*>(
                out + (size_t)(tb + mt * 16 + lm) * HID_C + n0));
        }
    }
}

extern "C" void kernel_launch(void* const* d_in, const int* in_sizes, int n_in,
                              void* d_out, int out_size, void* d_ws, size_t ws_size,
                              hipStream_t stream) {
    const float* E  = (const float*)d_in[0];
    const float* V  = (const float*)d_in[1];
    const int*   ei = (const int*)d_in[2];   // [2][N_EDGES] int32
    const float* W1 = (const float*)d_in[3];
    const float* b1 = (const float*)d_in[4];
    const float* W2 = (const float*)d_in[5];
    const float* b2 = (const float*)d_in[6];
    float* out = (float*)d_out;

    unsigned short* W1T = (unsigned short*)d_ws;                 // 256*192 bf16
    unsigned short* W2T = W1T + IN_DIM_C * HID_C;                // 256*256 bf16

    const int prep_total = IN_DIM_C * HID_C + HID_C * HID_C;     // 114688
    prep_weights_kernel<<<(prep_total + 255) / 256, 256, 0, stream>>>(W1, W2, W1T, W2T);

    const int nblocks = N_EDGES_C / (64 * T_TILES);              // 3125
    edge_mlp_kernel<<<nblocks, 1024, 0, stream>>>(
        E, V, ei, ei + N_EDGES_C, W1T, b1, W2T, b2, out);
}